// Round 7
// baseline (1510.620 us; speedup 1.0000x reference)
//
#include <hip/hip_runtime.h>

// Dims fixed by the reference
#define LAY 2
#define BATCH 64
#define TMAX 512
#define DIM 256
#define AST 264    // LDS activation row stride (bytes, fp8)
#define CHUNK 16   // pipeline handoff granularity (timesteps)

typedef float floatx4 __attribute__((ext_vector_type(4)));
typedef __bf16 bf16x8 __attribute__((ext_vector_type(8)));
#define MFMA_FP8  __builtin_amdgcn_mfma_f32_16x16x32_fp8_fp8
#define MFMA_BF16 __builtin_amdgcn_mfma_f32_16x16x32_bf16

// LDS-only barrier: orders ds ops (lgkmcnt) without draining vmcnt.
#define BAR_LDS() asm volatile("s_waitcnt lgkmcnt(0)\n\ts_barrier" ::: "memory")

// d_ws layout (requires ws >= ~74 MB)
#define OFF_WPW 0x60000     // bf16 B-frag W-mats, 6 x 128 KB  (ends 0x120000)
#define OFF_FLG 0x150000    // flags: [0..3] scan0, [4..35] projB (bg*8+p)
#define OFF_XP  0x200000    // layer-0 X-projections fp8, 25.2 MB
#define OFF_HP  0x1C00000   // layer-1 input projections fp8, 25.2 MB
#define OFF_HN  0x3600000   // hn0 bf16 [b*512+t][256], 16.8 MB

__device__ __forceinline__ unsigned short f2bf(float f) {
    unsigned int u = __float_as_uint(f);
    unsigned int r = u + 0x7fffu + ((u >> 16) & 1u);  // RNE
    return (unsigned short)(r >> 16);
}
__device__ __forceinline__ unsigned int pk2(float a, float b) {
    return (unsigned int)__builtin_amdgcn_cvt_pk_fp8_f32(a, b, 0, false);  // OCP e4m3 x2
}
__device__ __forceinline__ unsigned char f2q(float a) { return (unsigned char)(pk2(a, a) & 0xff); }
__device__ __forceinline__ void unp4(unsigned int u, float* f) {
    auto lo = __builtin_amdgcn_cvt_pk_f32_fp8((int)u, false);
    auto hi = __builtin_amdgcn_cvt_pk_f32_fp8((int)u, true);
    f[0] = lo[0]; f[1] = lo[1]; f[2] = hi[0]; f[3] = hi[1];
}
// sigmoid via raw v_rcp_f32 (1 instr vs ~10-instr IEEE div sequence).
__device__ __forceinline__ float sigf(float x) {
    return __builtin_amdgcn_rcpf(1.f + __expf(-x));
}
// tanh(y) = 2*sigmoid(2y) - 1
__device__ __forceinline__ float tanhfast2y(float twoy) { return 2.f * sigf(twoy) - 1.f; }

// ---------------------------------------------------------------------------
// Weight prep (identical math). Zeroes 64 pipeline flags and d_out.
// ---------------------------------------------------------------------------
__global__ void prep_weights(const float* __restrict__ Wz, const float* __restrict__ Wr,
                             const float* __restrict__ Wh, const float* __restrict__ Uz,
                             const float* __restrict__ Ur, const float* __restrict__ Uh,
                             unsigned char* __restrict__ ws, float* __restrict__ out) {
    int T = blockIdx.x * 256 + threadIdx.x;  // 1536*256 = 393216
    if (T == 0) out[0] = 0.f;
    if (T < 64) ((int*)(ws + OFF_FLG))[T] = 0;   // pipeline flags (ws re-poisoned each call)
    if (T < 196608) {  // U-mats, fp8
        int e = T & 3, half = (T >> 2) & 1, lane = (T >> 3) & 63;
        int kp = (T >> 9) & 3, nt = (T >> 11) & 15, mu = T >> 15;
        int g = mu % 3, l = mu / 3;
        const float* s = (g == 0 ? Uz : g == 1 ? Ur : Uh) + l * 65536;
        int n  = nt * 16 + (lane & 15);
        int k0 = (2 * kp + half) * 32 + (lane >> 4) * 8 + 2 * e;
        float w0 = s[(k0 << 8) + n] * 8.f;        // x8: dodge e4m3 denormals
        float w1 = s[((k0 + 1) << 8) + n] * 8.f;  // undone by 0.125 post-acc
        int addr = ((mu * 16 + nt) * 4 + kp) * 1024 + lane * 16 + half * 8 + 2 * e;
        *(unsigned short*)(ws + addr) = (unsigned short)(pk2(w0, w1) & 0xffff);
    } else {           // W-mats, bf16
        int T2 = T - 196608;
        int e = T2 & 3, lane = (T2 >> 2) & 63;
        int kf = (T2 >> 8) & 7, nt = (T2 >> 11) & 15, mw = T2 >> 15;
        int g = mw % 3, l = mw / 3;
        const float* s = (g == 0 ? Wz : g == 1 ? Wr : Wh) + l * 65536;
        int n  = nt * 16 + (lane & 15);
        int k0 = kf * 32 + (lane >> 4) * 8 + 2 * e;
        unsigned int v = (unsigned int)f2bf(s[(k0 << 8) + n]) |
                         ((unsigned int)f2bf(s[((k0 + 1) << 8) + n]) << 16);
        int addr = ((mw * 16 + nt) * 8 + kf) * 1024 + lane * 16 + 4 * e;
        *(unsigned int*)(ws + OFF_WPW + addr) = v;
    }
}

// ---------------------------------------------------------------------------
// Stage-A projection GEMM (standalone, unchanged): XP = x @ W(l0). Grid 2048.
// ---------------------------------------------------------------------------
template <int F32SRC>
__global__ __launch_bounds__(1024) void proj_kernel(const void* __restrict__ src,
                                                    const unsigned char* __restrict__ wpW,
                                                    unsigned int* __restrict__ xpo, int matbase) {
    const int bgt = blockIdx.x;
    const int t = bgt & 511, bg = bgt >> 9;
    const int tid = threadIdx.x, wave = tid >> 6, lane = tid & 63;
    const int l15 = lane & 15, quad = lane >> 4;
    const size_t rowoff = ((size_t)(bg * 16 + l15) * 512 + t) * 256;

    bf16x8 af[8];
    if (F32SRC) {
        const float* s = (const float*)src + rowoff;
#pragma unroll
        for (int kf = 0; kf < 8; ++kf) {
            float4 a = *(const float4*)(s + kf * 32 + quad * 8);
            float4 b = *(const float4*)(s + kf * 32 + quad * 8 + 4);
            union { unsigned short u[8]; bf16x8 v; } cv;
            cv.u[0] = f2bf(a.x); cv.u[1] = f2bf(a.y); cv.u[2] = f2bf(a.z); cv.u[3] = f2bf(a.w);
            cv.u[4] = f2bf(b.x); cv.u[5] = f2bf(b.y); cv.u[6] = f2bf(b.z); cv.u[7] = f2bf(b.w);
            af[kf] = cv.v;
        }
    } else {
        const unsigned short* s = (const unsigned short*)src + rowoff;
#pragma unroll
        for (int kf = 0; kf < 8; ++kf) af[kf] = *(const bf16x8*)(s + kf * 32 + quad * 8);
    }

    floatx4 az = {0.f, 0.f, 0.f, 0.f}, ar = az, ah = az;
    const unsigned char* bz = wpW + (size_t)(((matbase + 0) * 16 + wave) * 8) * 1024 + lane * 16;
    const unsigned char* br = wpW + (size_t)(((matbase + 1) * 16 + wave) * 8) * 1024 + lane * 16;
    const unsigned char* bh = wpW + (size_t)(((matbase + 2) * 16 + wave) * 8) * 1024 + lane * 16;
#pragma unroll
    for (int kf = 0; kf < 8; ++kf) {
        az = MFMA_BF16(af[kf], *(const bf16x8*)(bz + kf * 1024), az, 0, 0, 0);
        ar = MFMA_BF16(af[kf], *(const bf16x8*)(br + kf * 1024), ar, 0, 0, 0);
        ah = MFMA_BF16(af[kf], *(const bf16x8*)(bh + kf * 1024), ah, 0, 0, 0);
    }
    const size_t ob = (size_t)bgt * 3072 + wave * 64 + lane;
    xpo[ob]        = pk2(16.f * az[0], 16.f * az[1]) | (pk2(16.f * az[2], 16.f * az[3]) << 16);
    xpo[ob + 1024] = pk2(16.f * ar[0], 16.f * ar[1]) | (pk2(16.f * ar[2], 16.f * ar[3]) << 16);
    xpo[ob + 2048] = pk2(16.f * ah[0], 16.f * ah[1]) | (pk2(16.f * ah[2], 16.f * ah[3]) << 16);
}

// ---------------------------------------------------------------------------
// GRU scan body, 8 waves x 2 col-tiles per wave (512 threads). Each wave
// reads the shared A-fragment (full 16x256 activation) ONCE and feeds two
// 16-col output tiles -> sf/rf LDS traffic halves vs 16-wave layout, and the
// two per-tile MFMA chains interleave (free 2-way ILP). NWF>0: wait on MIN
// of NWF upstream flags. POST: publish pflag per CHUNK.
// ---------------------------------------------------------------------------
template <int SCORE, int NWF, int POST>
__device__ __forceinline__ void scan_body(
    const unsigned int* __restrict__ xp, const unsigned char* __restrict__ wpU,
    int lbase, int bg, unsigned short* __restrict__ hnout,
    const int* __restrict__ xlen, const float* __restrict__ xlab,
    const float* __restrict__ Wo, float* __restrict__ out,
    int* wflags, int* pflag,
    unsigned char (*s1q)[AST], unsigned char (*rsq)[AST], float (*s1o)[264],
    float* wo1s, int* s_rdy, int tmax)
{
    const int tid = threadIdx.x, wave = tid >> 6, lane = tid & 63;
    const int l15 = lane & 15, quad = lane >> 4;
    const int b0 = bg * 16;

    for (int i = tid; i < 16 * AST; i += 512) ((unsigned char*)s1q)[i] = 0;
    if (SCORE && tid < DIM) wo1s[tid] = Wo[2 * tid + 1];

    // score bookkeeping: wave w owns rows w and w+8
    int len0 = 0, len1 = 0;
    float lab0 = 0.f, lab1 = 0.f, acc0 = 0.f, acc1 = 0.f;
    if (SCORE) {
        len0 = xlen[b0 + wave];     len1 = xlen[b0 + 8 + wave];
        lab0 = xlab[b0 + wave];     lab1 = xlab[b0 + 8 + wave];
    }

    const int ntA = wave * 2, ntB = ntA + 1;
    const int cA = ntA * 16 + l15, cB = cA + 16, rowb = quad * 4;

    // register-resident U fragments for BOTH 16-col tiles (6 x 8 longs)
    long uzA[8], urA[8], uhA[8], uzB[8], urB[8], uhB[8];
    {
        const unsigned char* pzA = wpU + (size_t)(((lbase + 0) * 16 + ntA) * 4) * 1024 + lane * 16;
        const unsigned char* prA = wpU + (size_t)(((lbase + 1) * 16 + ntA) * 4) * 1024 + lane * 16;
        const unsigned char* phA = wpU + (size_t)(((lbase + 2) * 16 + ntA) * 4) * 1024 + lane * 16;
        const unsigned char* pzB = wpU + (size_t)(((lbase + 0) * 16 + ntB) * 4) * 1024 + lane * 16;
        const unsigned char* prB = wpU + (size_t)(((lbase + 1) * 16 + ntB) * 4) * 1024 + lane * 16;
        const unsigned char* phB = wpU + (size_t)(((lbase + 2) * 16 + ntB) * 4) * 1024 + lane * 16;
#pragma unroll
        for (int kf = 0; kf < 8; ++kf) {
            int o = (kf >> 1) * 1024 + (kf & 1) * 8;
            uzA[kf] = *(const long*)(pzA + o);
            urA[kf] = *(const long*)(prA + o);
            uhA[kf] = *(const long*)(phA + o);
            uzB[kf] = *(const long*)(pzB + o);
            urB[kf] = *(const long*)(prB + o);
            uhB[kf] = *(const long*)(phB + o);
        }
    }
    float s1A[4] = {}, s1B[4] = {};
    int ready = 0;
    __syncthreads();

    for (int t = 0; t < tmax; ++t) {
        if (NWF > 0 && t >= ready) {
            if (tid == 0) {
                int vv, g = 0;
                for (;;) {
                    vv = 1 << 30;
#pragma unroll
                    for (int q = 0; q < (NWF > 0 ? NWF : 1); ++q) {
                        int m = __hip_atomic_load(wflags + q, __ATOMIC_RELAXED, __HIP_MEMORY_SCOPE_AGENT);
                        vv = m < vv ? m : vv;
                    }
                    if (vv > t || ++g > (1 << 19)) break;   // fail visibly, never hang
                    __builtin_amdgcn_s_sleep(2);
                }
                __threadfence();          // agent acquire before data reads
                *s_rdy = vv > t ? vv : t + 1;
            }
            __syncthreads();
            ready = *s_rdy;
        }

        const unsigned int* xpt = xp + (size_t)(bg * 512 + t) * 3072 + lane;
        unsigned int xzA = xpt[ntA * 64],        xzB = xpt[ntB * 64];
        unsigned int xrA = xpt[1024 + ntA * 64], xrB = xpt[1024 + ntB * 64];
        unsigned int xhA = xpt[2048 + ntA * 64], xhB = xpt[2048 + ntB * 64];

        // ---- phase 1: r (critical path) + z-MFMAs; A-frag shared by tiles ----
        long sf[8];
#pragma unroll
        for (int kf = 0; kf < 8; ++kf) sf[kf] = *(const long*)&s1q[l15][kf * 32 + quad * 8];
        floatx4 zer = {0.f, 0.f, 0.f, 0.f};
        floatx4 raA = zer, raB = zer, zaA = zer, zaB = zer;
#pragma unroll
        for (int kf = 0; kf < 8; ++kf) {
            raA = MFMA_FP8(sf[kf], urA[kf], raA, 0, 0, 0);
            raB = MFMA_FP8(sf[kf], urB[kf], raB, 0, 0, 0);
            zaA = MFMA_FP8(sf[kf], uzA[kf], zaA, 0, 0, 0);
            zaB = MFMA_FP8(sf[kf], uzB[kf], zaB, 0, 0, 0);
        }
        float xrfA[4], xrfB[4];
        unp4(xrA, xrfA); unp4(xrB, xrfB);
#pragma unroll
        for (int i = 0; i < 4; ++i) {
            float rA_ = sigf(0.125f * raA[i] + 0.0625f * xrfA[i]);
            float rB_ = sigf(0.125f * raB[i] + 0.0625f * xrfB[i]);
            rsq[rowb + i][cA] = f2q(rA_ * s1A[i]);
            rsq[rowb + i][cB] = f2q(rB_ * s1B[i]);
        }
        BAR_LDS();   // LDS-only: XP loads / HN stores stay in flight

        // ---- phase 2: h; z-sigmoid overlaps the Uh MFMAs ----
        long rf[8];
#pragma unroll
        for (int kf = 0; kf < 8; ++kf) rf[kf] = *(const long*)&rsq[l15][kf * 32 + quad * 8];
        floatx4 haA = zer, haB = zer;
#pragma unroll
        for (int kf = 0; kf < 8; ++kf) {
            haA = MFMA_FP8(rf[kf], uhA[kf], haA, 0, 0, 0);
            haB = MFMA_FP8(rf[kf], uhB[kf], haB, 0, 0, 0);
        }
        float xzfA[4], xzfB[4], xhfA[4], xhfB[4];
        unp4(xzA, xzfA); unp4(xzB, xzfB); unp4(xhA, xhfA); unp4(xhB, xhfB);
#pragma unroll
        for (int i = 0; i < 4; ++i) {
            float zA_ = sigf(0.125f * zaA[i] + 0.0625f * xzfA[i]);
            float hA_ = tanhfast2y(0.25f * haA[i] + 0.125f * xhfA[i]);
            float hnA = (1.f - zA_) * s1A[i] + zA_ * hA_;
            s1A[i] = hnA;
            s1q[rowb + i][cA] = f2q(hnA);
            s1o[rowb + i][cA] = hnA;
            float zB_ = sigf(0.125f * zaB[i] + 0.0625f * xzfB[i]);
            float hB_ = tanhfast2y(0.25f * haB[i] + 0.125f * xhfB[i]);
            float hnB = (1.f - zB_) * s1B[i] + zB_ * hB_;
            s1B[i] = hnB;
            s1q[rowb + i][cB] = f2q(hnB);
            s1o[rowb + i][cB] = hnB;
        }
        BAR_LDS();   // LDS-only

        if (!SCORE) {
            // cooperative hn0 write: 512 threads, 16 B each; coalesced 16B stores
            const int r = tid >> 5, c = (tid & 31) * 8;
            float4 f0 = *(const float4*)&s1o[r][c];
            float4 f1 = *(const float4*)&s1o[r][c + 4];
            uint4 o4;
            o4.x = f2bf(f0.x) | ((unsigned)f2bf(f0.y) << 16);
            o4.y = f2bf(f0.z) | ((unsigned)f2bf(f0.w) << 16);
            o4.z = f2bf(f1.x) | ((unsigned)f2bf(f1.y) << 16);
            o4.w = f2bf(f1.z) | ((unsigned)f2bf(f1.w) << 16);
            *(uint4*)(hnout + ((size_t)(b0 + r) * 512 + t) * 256 + c) = o4;
        } else {
            // score spread: wave w handles rows w and w+8 (4 FMA + reduce each)
            const float4 wv = *(const float4*)&wo1s[lane * 4];
            const float4 s0 = *(const float4*)&s1o[wave][lane * 4];
            const float4 s1v = *(const float4*)&s1o[8 + wave][lane * 4];
            float p0 = s0.x * wv.x;  p0 = fmaf(s0.y, wv.y, p0);
            p0 = fmaf(s0.z, wv.z, p0); p0 = fmaf(s0.w, wv.w, p0);
            float p1 = s1v.x * wv.x; p1 = fmaf(s1v.y, wv.y, p1);
            p1 = fmaf(s1v.z, wv.z, p1); p1 = fmaf(s1v.w, wv.w, p1);
#pragma unroll
            for (int o = 1; o < 64; o <<= 1) {
                p0 += __shfl_xor(p0, o);
                p1 += __shfl_xor(p1, o);
            }
            if (lane == 0) {
                if (t < len0) { float sc = sigf(p0); float d = lab0 - sc; acc0 = fmaf(d, d, acc0); }
                if (t < len1) { float sc = sigf(p1); float d = lab1 - sc; acc1 = fmaf(d, d, acc1); }
            }
        }

        if (POST && (((t & (CHUNK - 1)) == (CHUNK - 1)) || t == tmax - 1)) {
            __syncthreads();   // FULL drain: all waves' HN stores (vmcnt0) before fence
            if (tid == 0) {
                __threadfence();   // agent release: push chunk data to coherent point
                __hip_atomic_store(pflag, t + 1, __ATOMIC_RELEASE, __HIP_MEMORY_SCOPE_AGENT);
            }
        }
    }

    if (SCORE && lane == 0) atomicAdd(out, acc0 + acc1);
}

// ---------------------------------------------------------------------------
// Fused 3-stage pipeline, 40 WGs x 512 threads:
//   blocks 0-3  : layer-0 scan (8 waves x 2 tiles; posts flags[bg] per chunk)
//   blocks 4-35 : projB, 8 WGs per bg; WG p owns t in {base+2p, base+2p+1} of
//                 each chunk; waits flags[bg], posts flags[4+bg*8+p]
//   blocks 36-39: layer-1 scan + loss (waits MIN of the bg's 8 projB flags)
// ---------------------------------------------------------------------------
__global__ __launch_bounds__(512, 2) void fused_pipeline(
    const unsigned int* __restrict__ XP, unsigned int* __restrict__ HP,
    const unsigned char* __restrict__ wpU, const unsigned char* __restrict__ wpW,
    unsigned short* __restrict__ HN,
    const int* __restrict__ xlen, const float* __restrict__ xlab,
    const float* __restrict__ Wo, float* __restrict__ out, int* flags)
{
    __shared__ __align__(16) unsigned char s1q[16][AST];
    __shared__ __align__(16) unsigned char rsq[16][AST];
    __shared__ __align__(16) float s1o[16][264];
    __shared__ float wo1s[DIM];
    __shared__ int s_rdy;

    const int bid = blockIdx.x;
    int role, bg, p = 0;
    if (bid < 4)       { role = 0; bg = bid; }
    else if (bid < 36) { role = 1; bg = (bid - 4) >> 3; p = (bid - 4) & 7; }
    else               { role = 2; bg = bid - 36; }

    const int tid = threadIdx.x, wave = tid >> 6, lane = tid & 63;
    const int l15 = lane & 15, quad = lane >> 4;
    const int b0 = bg * 16;

    // uniform tmax = max xlen over this bg's 16 rows (same in all stages)
    int v = xlen[b0 + l15];
#pragma unroll
    for (int o = 1; o < 16; o <<= 1) v = max(v, __shfl_xor(v, o));
    const int tmax = __builtin_amdgcn_readfirstlane(v);

    if (role == 0) {
        scan_body<0, 0, 1>(XP, wpU, 0, bg, HN, xlen, xlab, Wo, out,
                           nullptr, flags + bg, s1q, rsq, s1o, wo1s, &s_rdy, tmax);
    } else if (role == 2) {
        scan_body<1, 8, 0>(HP, wpU, 3, bg, nullptr, xlen, xlab, Wo, out,
                           flags + 4 + bg * 8, nullptr, s1q, rsq, s1o, wo1s, &s_rdy, tmax);
    } else {
        // ---- projB: HP[t] = HN[t] @ W(l1); 8 waves x 2 tiles; 2 t per chunk ----
        int* wf = flags + bg;
        int* pf = flags + 4 + bg * 8 + p;
        const int ntA = wave * 2, ntB = ntA + 1;
        const unsigned char* bzA = wpW + (size_t)(((3 + 0) * 16 + ntA) * 8) * 1024 + lane * 16;
        const unsigned char* brA = wpW + (size_t)(((3 + 1) * 16 + ntA) * 8) * 1024 + lane * 16;
        const unsigned char* bhA = wpW + (size_t)(((3 + 2) * 16 + ntA) * 8) * 1024 + lane * 16;
        const unsigned char* bzB = wpW + (size_t)(((3 + 0) * 16 + ntB) * 8) * 1024 + lane * 16;
        const unsigned char* brB = wpW + (size_t)(((3 + 1) * 16 + ntB) * 8) * 1024 + lane * 16;
        const unsigned char* bhB = wpW + (size_t)(((3 + 2) * 16 + ntB) * 8) * 1024 + lane * 16;
        for (int base = 0; base < tmax; base += CHUNK) {
            const int target = (base + CHUNK < tmax) ? base + CHUNK : tmax;
            if (tid == 0) {
                int vv, g = 0;
                for (;;) {
                    vv = __hip_atomic_load(wf, __ATOMIC_RELAXED, __HIP_MEMORY_SCOPE_AGENT);
                    if (vv >= target || ++g > (1 << 19)) break;
                    __builtin_amdgcn_s_sleep(2);
                }
                __threadfence();   // acquire: see scan0's HN chunk
            }
            __syncthreads();       // no wave reads HN before the inv

            const int t0 = base + p * 2;
            const int t1 = (t0 + 2 < tmax) ? t0 + 2 : tmax;
            for (int t = t0; t < t1; ++t) {
                const unsigned short* sA = HN + ((size_t)(b0 + l15) * 512 + t) * 256;
                bf16x8 af[8];
#pragma unroll
                for (int kf = 0; kf < 8; ++kf) af[kf] = *(const bf16x8*)(sA + kf * 32 + quad * 8);
                floatx4 zer = {0.f, 0.f, 0.f, 0.f};
                floatx4 azA = zer, arA = zer, ahA = zer, azB = zer, arB = zer, ahB = zer;
#pragma unroll
                for (int kf = 0; kf < 8; ++kf) {
                    azA = MFMA_BF16(af[kf], *(const bf16x8*)(bzA + kf * 1024), azA, 0, 0, 0);
                    arA = MFMA_BF16(af[kf], *(const bf16x8*)(brA + kf * 1024), arA, 0, 0, 0);
                    ahA = MFMA_BF16(af[kf], *(const bf16x8*)(bhA + kf * 1024), ahA, 0, 0, 0);
                    azB = MFMA_BF16(af[kf], *(const bf16x8*)(bzB + kf * 1024), azB, 0, 0, 0);
                    arB = MFMA_BF16(af[kf], *(const bf16x8*)(brB + kf * 1024), arB, 0, 0, 0);
                    ahB = MFMA_BF16(af[kf], *(const bf16x8*)(bhB + kf * 1024), ahB, 0, 0, 0);
                }
                const size_t obA = (size_t)(bg * 512 + t) * 3072 + ntA * 64 + lane;
                const size_t obB = obA + 64;
                HP[obA]        = pk2(16.f * azA[0], 16.f * azA[1]) | (pk2(16.f * azA[2], 16.f * azA[3]) << 16);
                HP[obA + 1024] = pk2(16.f * arA[0], 16.f * arA[1]) | (pk2(16.f * arA[2], 16.f * arA[3]) << 16);
                HP[obA + 2048] = pk2(16.f * ahA[0], 16.f * ahA[1]) | (pk2(16.f * ahA[2], 16.f * ahA[3]) << 16);
                HP[obB]        = pk2(16.f * azB[0], 16.f * azB[1]) | (pk2(16.f * azB[2], 16.f * azB[3]) << 16);
                HP[obB + 1024] = pk2(16.f * arB[0], 16.f * arB[1]) | (pk2(16.f * arB[2], 16.f * arB[3]) << 16);
                HP[obB + 2048] = pk2(16.f * ahB[0], 16.f * ahB[1]) | (pk2(16.f * ahB[2], 16.f * ahB[3]) << 16);
            }

            __syncthreads();   // all waves' HP stores drained (vmcnt0 before barrier)
            if (tid == 0) {
                __threadfence();   // release: push HP chunk to coherent point
                __hip_atomic_store(pf, base + CHUNK, __ATOMIC_RELEASE, __HIP_MEMORY_SCOPE_AGENT);
            }
        }
    }
}

extern "C" void kernel_launch(void* const* d_in, const int* in_sizes, int n_in,
                              void* d_out, int out_size, void* d_ws, size_t ws_size,
                              hipStream_t stream) {
    const float* x    = (const float*)d_in[0];
    const int*   xlen = (const int*)d_in[1];
    const float* xlab = (const float*)d_in[2];
    const float* Wz   = (const float*)d_in[3];
    const float* Uz   = (const float*)d_in[4];
    const float* Wr   = (const float*)d_in[5];
    const float* Ur   = (const float*)d_in[6];
    const float* Wh   = (const float*)d_in[7];
    const float* Uh   = (const float*)d_in[8];
    const float* Wo   = (const float*)d_in[9];
    float* out = (float*)d_out;

    unsigned char* ws  = (unsigned char*)d_ws;
    unsigned char* wpU = ws;                                 // fp8 U-frags, 384 KB
    unsigned char* wpW = ws + OFF_WPW;                       // bf16 W-frags, 768 KB
    int*           FLG = (int*)(ws + OFF_FLG);               // pipeline flags
    unsigned int*  XP  = (unsigned int*)(ws + OFF_XP);       // 25.2 MB
    unsigned int*  HP  = (unsigned int*)(ws + OFF_HP);       // 25.2 MB
    unsigned short* HN = (unsigned short*)(ws + OFF_HN);     // 16.8 MB

    // ws re-poisoned every call -> rebuild everything (incl. flags) each time.
    prep_weights<<<1536, 256, 0, stream>>>(Wz, Wr, Wh, Uz, Ur, Uh, ws, out);
    proj_kernel<1><<<2048, 1024, 0, stream>>>(x, wpW, XP, 0);   // A: x @ W(l0)
    fused_pipeline<<<40, 512, 0, stream>>>(XP, HP, wpU, wpW, HN,
                                           xlen, xlab, Wo, out, FLG);
}